// Round 10
// baseline (7632.160 us; speedup 1.0000x reference)
//
#include <hip/hip_runtime.h>
#include <hip/hip_bf16.h>
#include <math.h>

#define BB 64
#define SS 64
#define DA 512
#define DM 2048
#define MM 25
#define NH 8
#define HD 64
#define NS 512
#define NOUT 1000
#define TT 50
#define HN 32
#define KTOT 2560
#define NOUT2 4096
#define NPAD 1024
#define SB2 ((size_t)BB*NS)

typedef __attribute__((ext_vector_type(8))) short bf16x8_t;
typedef __attribute__((ext_vector_type(8))) unsigned short u16x8_t;
typedef __attribute__((ext_vector_type(4))) float f32x4_t;

__device__ inline float bfs2f(unsigned short u){
    unsigned int x = ((unsigned int)u) << 16;
    return __uint_as_float(x);
}
__device__ inline unsigned short f2bfu(float v){
    __hip_bfloat16 h = __float2bfloat16(v);
    return *reinterpret_cast<unsigned short*>(&h);
}
__device__ inline float gelu_tanh(float x){
    float x3 = x*x*x;
    float u = 0.7978845608028654f*(x + 0.044715f*x3);
    float eu = __expf(2.f*u);
    float th = 1.f - 2.f/(eu + 1.f);
    return 0.5f*x*(1.0f + th);
}

// ---------------- workspace layout (float units) ----------------
static const size_t OFF_K     = 0;                                 // bf16 [4096][512]
static const size_t OFF_V     = OFF_K     + 1048576;
static const size_t OFF_WCT   = OFF_V     + 1048576;               // bf16 [4096][2560]
static const size_t OFF_WC1B  = OFF_WCT   + 5242880;               // bf16 [512][512]
static const size_t OFF_WOUTT = OFF_WC1B  + 131072;                // bf16 [1024][512]
static const size_t OFF_NW1B  = OFF_WOUTT + 262144;                // bf16 [2048][800]
static const size_t OFF_WFT   = OFF_NW1B  + 819200;                // bf16 [512][512] (transposed)
static const size_t OFF_WKT   = OFF_WFT   + 131072;
static const size_t OFF_WVT   = OFF_WKT   + 131072;
static const size_t OFF_WQT   = OFF_WVT   + 131072;
static const size_t OFF_WQPB  = OFF_WQT   + 131072;                // bf16 row-major
static const size_t OFF_WOB   = OFF_WQPB  + 131072;                // bf16 row-major
static const size_t OFF_BC1   = OFF_WOB   + 131072;
static const size_t OFF_BC2   = OFF_BC1   + 512;
static const size_t OFF_BOUTP = OFF_BC2   + 4096;
static const size_t OFF_AA    = OFF_BOUTP + 1024;                  // f32 2x[64][512]
static const size_t OFF_BA    = OFF_AA    + 2*SB2;
static const size_t OFF_AO    = OFF_BA    + 2*SB2;
static const size_t OFF_BO    = OFF_AO    + 2*SB2;
static const size_t OFF_ATT   = OFF_BO    + 2*SB2;                 // bf16 [64][512]
static const size_t OFF_ACTB  = OFF_ATT   + 16384;                 // bf16 [b][d]
static const size_t OFF_ACTF  = OFF_ACTB  + 65536;                 // f32 [d][b]
static const size_t OFF_SBUF  = OFF_ACTF  + 131072;                // f32 [b][2048]
static const size_t OFF_STATS = OFF_SBUF  + 131072;                // f32 [64][2] (sum, sumsq)
static const size_t OFF_TRB   = OFF_STATS + 128;                   // bf16 [25][2048][64]
static const size_t OFF_PREDA = OFF_TRB   + 1638400;               // bf16 [50][64][1024]
static const size_t OFF_END   = OFF_PREDA + 1638400;
// setup-only aliases (dead before tick loop writes these regions):
static const size_t OFF_XB    = OFF_PREDA;   // bf16 [4096][512]
static const size_t OFF_KV    = OFF_TRB;     // bf16 [4096][512]
static const size_t OFF_WS1T  = OFF_TRB;     // bf16 [4096][512]  (used after KV is dead)

// ---------------- setup kernels ----------------
// C[m][n](ldc,bf16) = A[m][k](lda,bf16) @ BT[n][k](ldbt,bf16) + bias(f32,optional)
// grid (N/64, M/64), 256 threads, K multiple of 64.
__global__ __launch_bounds__(256) void mgemm(
        const unsigned short* __restrict__ A, int lda,
        const unsigned short* __restrict__ BT, int ldbt,
        const float* __restrict__ bias,
        unsigned short* __restrict__ C, int ldc, int K)
{
    __shared__ unsigned short Al[64][72];
    __shared__ unsigned short Bl[64][72];
    int cg = blockIdx.x, rg = blockIdx.y, tid = threadIdx.x;
    int w = tid >> 6, lane = tid & 63;
    int m0 = rg*64, n0 = cg*64;
    f32x4_t acc[4];
    #pragma unroll
    for (int t2 = 0; t2 < 4; ++t2) acc[t2] = (f32x4_t){0.f,0.f,0.f,0.f};
    for (int k0 = 0; k0 < K; k0 += 64){
        #pragma unroll
        for (int ld = 0; ld < 2; ++ld){
            int idx = tid + ld*256;
            int row = idx >> 3, kg = (idx & 7)*8;
            *reinterpret_cast<uint4*>(&Bl[row][kg]) =
                *reinterpret_cast<const uint4*>(&BT[(size_t)(n0+row)*ldbt + k0 + kg]);
            *reinterpret_cast<uint4*>(&Al[row][kg]) =
                *reinterpret_cast<const uint4*>(&A[(size_t)(m0+row)*lda + k0 + kg]);
        }
        __syncthreads();
        int arow = w*16 + (lane & 15);
        int koff = (lane >> 4)*8;
        bf16x8_t a0 = *reinterpret_cast<const bf16x8_t*>(&Al[arow][koff]);
        bf16x8_t a1 = *reinterpret_cast<const bf16x8_t*>(&Al[arow][32 + koff]);
        #pragma unroll
        for (int t2 = 0; t2 < 4; ++t2){
            int brow = t2*16 + (lane & 15);
            bf16x8_t b0 = *reinterpret_cast<const bf16x8_t*>(&Bl[brow][koff]);
            bf16x8_t b1 = *reinterpret_cast<const bf16x8_t*>(&Bl[brow][32 + koff]);
            acc[t2] = __builtin_amdgcn_mfma_f32_16x16x32_bf16(a0, b0, acc[t2], 0, 0, 0);
            acc[t2] = __builtin_amdgcn_mfma_f32_16x16x32_bf16(a1, b1, acc[t2], 0, 0, 0);
        }
        __syncthreads();
    }
    int colb = lane & 15, rg4 = (lane >> 4)*4;
    #pragma unroll
    for (int t2 = 0; t2 < 4; ++t2){
        #pragma unroll
        for (int r = 0; r < 4; ++r){
            int row = m0 + w*16 + rg4 + r;
            int col = n0 + t2*16 + colb;
            float v = acc[t2][r];
            if (bias) v += bias[col];
            C[(size_t)row*ldc + col] = f2bfu(v);
        }
    }
}

// out[n][k] = bf16(in[k][n]); grid (cols/32, rows/32), 256 thr (32x8)
__global__ void tcvtb(const float* __restrict__ in, int ldin,
                      unsigned short* __restrict__ out, int ldout)
{
    __shared__ float tile[32][33];
    int bx = blockIdx.x, by = blockIdx.y;
    int tx = threadIdx.x & 31, ty = threadIdx.x >> 5;
    for (int i = 0; i < 4; ++i)
        tile[ty + i*8][tx] = in[(size_t)(by*32 + ty + i*8)*ldin + bx*32 + tx];
    __syncthreads();
    for (int i = 0; i < 4; ++i)
        out[(size_t)(bx*32 + ty + i*8)*ldout + by*32 + tx] = f2bfu(tile[tx][ty + i*8]);
}

// Ws1 rows 512..2559 -> WcT[n][512+r]
__global__ void tcvt_ws1(const float* __restrict__ Ws1, unsigned short* __restrict__ WcT)
{
    __shared__ float tile[32][33];
    int bx = blockIdx.x, by = blockIdx.y;
    int tx = threadIdx.x & 31, ty = threadIdx.x >> 5;
    for (int i = 0; i < 4; ++i){
        int r = by*32 + ty + i*8;
        tile[ty + i*8][tx] = Ws1[(size_t)(512 + r)*NOUT2 + bx*32 + tx];
    }
    __syncthreads();
    for (int i = 0; i < 4; ++i){
        int n = bx*32 + ty + i*8;
        int r = by*32 + tx;
        WcT[(size_t)n*KTOT + 512 + r] = f2bfu(tile[tx][ty + i*8]);
    }
}

__global__ void tcvt_wout(const float* __restrict__ Wout, const float* __restrict__ bout,
                          unsigned short* __restrict__ WoutT, float* __restrict__ boutp)
{
    int n = blockIdx.x;
    int tid = threadIdx.x;
    for (int k = tid; k < NS; k += 256)
        WoutT[(size_t)n*NS + k] = (n < NOUT) ? f2bfu(Wout[(size_t)k*NOUT + n]) : (unsigned short)0;
    if (tid == 0) boutp[n] = (n < NOUT) ? bout[n] : 0.f;
}

__global__ void bias_combo(const float* __restrict__ bvec, const float* __restrict__ W,
                           int ldw, const float* __restrict__ badd,
                           float* __restrict__ out, int N)
{
    int n = blockIdx.x*256 + threadIdx.x;
    if (n >= N) return;
    float acc = badd[n];
    for (int k = 0; k < 512; ++k) acc += bvec[k]*W[(size_t)k*ldw + n];
    out[n] = acc;
}

__global__ void cvt_bf16(const float* __restrict__ in, unsigned short* __restrict__ out, int n)
{
    int i = blockIdx.x*256 + threadIdx.x;
    if (i < n) out[i] = f2bfu(in[i]);
}

__global__ void init_state(const float* __restrict__ ss,
                           const int* __restrict__ ilo, const int* __restrict__ iro,
                           float* __restrict__ act_f, unsigned short* __restrict__ act_bf,
                           float* __restrict__ aA0, float* __restrict__ bA0,
                           float* __restrict__ aO0, float* __restrict__ bO0)
{
    int i = blockIdx.x*256 + threadIdx.x;
    if (i < BB*DM){
        int d = i >> 6, b = i & 63;
        float v = ss[d];
        act_f[(size_t)d*BB + b] = v;
        act_bf[(size_t)b*DM + d] = f2bfu(v);
    }
    if (i < BB*NS){
        int j = i & (NS-1);
        aA0[i] = 0.f; bA0[i] = 0.f;
        aO0[i] = ss[ilo[j]]*ss[iro[j]];
        bO0[i] = 1.f;
    }
}

// ---------------- per-tick kernels ----------------
// pred for tick tp: syO computed redundantly in-LDS per block; block 0 persists state.
__device__ void pred_body(char* smem, int pb,
                          const float* __restrict__ act_f,
                          float* __restrict__ aO, float* __restrict__ bO,
                          const int* __restrict__ ilo, const int* __restrict__ iro,
                          const float* __restrict__ dco,
                          const unsigned short* __restrict__ WoutT,
                          const float* __restrict__ boutp,
                          unsigned short* __restrict__ predA,
                          float* __restrict__ out_syo, int tp)
{
    unsigned short* Asy = (unsigned short*)smem;   // [64][72]
    const int tid = threadIdx.x, lane = tid & 63, w = tid >> 6;
    const int rf = w & 3, cf2 = (w >> 2)*2;
    const int colb = lane & 15, koff = (lane >> 4)*8, rg4 = (lane >> 4)*4;
    const int n0 = pb*64;
    const int rdn = tp & 1, wrn = 1 - rdn;
    f32x4_t acc0 = {0.f,0.f,0.f,0.f}, acc1 = {0.f,0.f,0.f,0.f};
    for (int ks = 0; ks < 8; ++ks){
        int jj = tid & 63, bq = tid >> 6;
        int j = ks*64 + jj;
        int ilj = ilo[j], irj = iro[j];
        float rr = __expf(-fminf(fmaxf(dco[j], 0.f), 15.f));
        #pragma unroll
        for (int p = 0; p < 8; ++p){
            int b = p*8 + bq;
            float pair = act_f[(size_t)ilj*BB + b]*act_f[(size_t)irj*BB + b];
            size_t o = (size_t)b*NS + j;
            float a  = rr*aO[(size_t)rdn*SB2 + o] + pair;
            float be = rr*bO[(size_t)rdn*SB2 + o] + 1.f;
            float s = a*rsqrtf(be);
            Asy[b*72 + jj] = f2bfu(s);
            if (pb == 0){
                aO[(size_t)wrn*SB2 + o] = a;
                bO[(size_t)wrn*SB2 + o] = be;
                if (tp == TT-1) out_syo[o] = s;
            }
        }
        __syncthreads();
        int arow = rf*16 + colb;
        bf16x8_t a0 = *(const bf16x8_t*)&Asy[arow*72 + koff];
        bf16x8_t a1 = *(const bf16x8_t*)&Asy[arow*72 + 32 + koff];
        int br0 = n0 + cf2*16 + colb, br1 = br0 + 16;
        bf16x8_t b00 = *(const bf16x8_t*)&WoutT[(size_t)br0*NS + ks*64 + koff];
        bf16x8_t b01 = *(const bf16x8_t*)&WoutT[(size_t)br0*NS + ks*64 + 32 + koff];
        bf16x8_t b10 = *(const bf16x8_t*)&WoutT[(size_t)br1*NS + ks*64 + koff];
        bf16x8_t b11 = *(const bf16x8_t*)&WoutT[(size_t)br1*NS + ks*64 + 32 + koff];
        acc0 = __builtin_amdgcn_mfma_f32_16x16x32_bf16(a0, b00, acc0, 0, 0, 0);
        acc0 = __builtin_amdgcn_mfma_f32_16x16x32_bf16(a1, b01, acc0, 0, 0, 0);
        acc1 = __builtin_amdgcn_mfma_f32_16x16x32_bf16(a0, b10, acc1, 0, 0, 0);
        acc1 = __builtin_amdgcn_mfma_f32_16x16x32_bf16(a1, b11, acc1, 0, 0, 0);
        __syncthreads();
    }
    unsigned short* pa = predA + (size_t)tp*BB*NPAD;
    #pragma unroll
    for (int r = 0; r < 4; ++r){
        int row = rf*16 + rg4 + r;
        int c0 = n0 + cf2*16 + colb, c1 = c0 + 16;
        pa[(size_t)row*NPAD + c0] = f2bfu(acc0[r] + boutp[c0]);
        pa[(size_t)row*NPAD + c1] = f2bfu(acc1[r] + boutp[c1]);
    }
}

// blocks 0..63: syncA(t)+Qh+attention; blocks 64..79: pred(t-1); block 63 zeroes stats
__global__ __launch_bounds__(512) void tick_head(
        const float* __restrict__ act_f,
        float* __restrict__ aA, float* __restrict__ bA,
        float* __restrict__ aO, float* __restrict__ bO,
        const int* __restrict__ ila, const int* __restrict__ ira,
        const int* __restrict__ ilo, const int* __restrict__ iro,
        const float* __restrict__ dca, const float* __restrict__ dco,
        const unsigned short* __restrict__ Wc1b, const float* __restrict__ bc1,
        const unsigned short* __restrict__ Kb, const unsigned short* __restrict__ Vb,
        unsigned short* __restrict__ att,
        const unsigned short* __restrict__ WoutT, const float* __restrict__ boutp,
        unsigned short* __restrict__ predA, float* __restrict__ out_syo,
        float* __restrict__ stats,
        int t, int do_pred)
{
    __shared__ __align__(16) char smem[20480];
    const int bid = blockIdx.x, tid = threadIdx.x;
    const int lane = tid & 63, w = tid >> 6;
    if (bid < 64){
        if (bid == 63 && tid < 128) stats[tid] = 0.f;
        int h = bid >> 3, bg = bid & 7;
        float* sy  = (float*)smem;          // [8][512]
        float* q   = sy + 8*NS;             // [8][64]
        float* wgt = q + 8*64;              // [8][64]
        int rdn = t & 1, wrn = 1 - rdn;
        for (int i = tid; i < 8*NS; i += 512){
            int r = i >> 9, j = i & (NS-1);
            int b = bg*8 + r;
            float pair = act_f[(size_t)ila[j]*BB + b]*act_f[(size_t)ira[j]*BB + b];
            float rr = __expf(-fminf(fmaxf(dca[j], 0.f), 15.f));
            size_t o = (size_t)b*NS + j;
            float a  = rr*aA[(size_t)rdn*SB2 + o] + pair;
            float be = rr*bA[(size_t)rdn*SB2 + o] + 1.f;
            sy[i] = a*rsqrtf(be);
            if (h == 0){ aA[(size_t)wrn*SB2 + o] = a; bA[(size_t)wrn*SB2 + o] = be; }
        }
        __syncthreads();
        {   // Qh: r = w (batch), c = lane
            int c = lane, r = w;
            int col = h*HD + c;
            float acc = bc1[col];
            const unsigned short* wp = Wc1b + col;
            #pragma unroll 8
            for (int k = 0; k < NS; ++k) acc += sy[r*NS + k]*bfs2f(wp[(size_t)k*DA]);
            q[r*64 + c] = acc;
        }
        __syncthreads();
        {   // scores + softmax: wave r handles batch bg*8+r, lane = s
            int r = w, s = tid & 63;
            int b = bg*8 + r;
            const unsigned short* kp = Kb + (size_t)(b*SS + s)*DA + h*HD;
            float sc = 0.f;
            #pragma unroll
            for (int dg = 0; dg < 8; ++dg){
                u16x8_t kv = *(const u16x8_t*)(kp + dg*8);
                #pragma unroll
                for (int u = 0; u < 8; ++u) sc += q[r*64 + dg*8 + u]*bfs2f(kv[u]);
            }
            sc *= 0.125f;
            float m = sc;
            for (int o = 32; o; o >>= 1) m = fmaxf(m, __shfl_xor(m, o, 64));
            float e = __expf(sc - m);
            float sum = e;
            for (int o = 32; o; o >>= 1) sum += __shfl_xor(sum, o, 64);
            wgt[r*64 + s] = e/sum;
        }
        __syncthreads();
        {   // PV: wave r, lane = d
            int r = w, d = lane;
            int b = bg*8 + r;
            const unsigned short* vp = Vb + (size_t)(b*SS)*DA + h*HD + d;
            float o = 0.f;
            #pragma unroll 8
            for (int s = 0; s < SS; ++s) o += wgt[r*64 + s]*bfs2f(vp[(size_t)s*DA]);
            att[(size_t)b*DA + h*HD + d] = f2bfu(o);
        }
    } else if (do_pred){
        pred_body(smem, bid - 64, act_f, aO, bO, ilo, iro, dco,
                  WoutT, boutp, predA, out_syo, t - 1);
    }
}

__global__ __launch_bounds__(512) void pred_fin(
        const float* __restrict__ act_f,
        float* __restrict__ aO, float* __restrict__ bO,
        const int* __restrict__ ilo, const int* __restrict__ iro,
        const float* __restrict__ dco,
        const unsigned short* __restrict__ WoutT, const float* __restrict__ boutp,
        unsigned short* __restrict__ predA, float* __restrict__ out_syo)
{
    __shared__ __align__(16) char smem[10240];
    pred_body(smem, blockIdx.x, act_f, aO, bO, ilo, iro, dco,
              WoutT, boutp, predA, out_syo, TT - 1);
}

// Fused hgemm + GLU + LN-stats atomics.  256 blocks x 256 thr; block handles
// 8 column-pairs (n0..n0+7, 2048+n0..+7) with a mixed 16-row B tile, full K.
__global__ __launch_bounds__(256) void hgemm_glu(
        const unsigned short* __restrict__ attu, const unsigned short* __restrict__ actu,
        const unsigned short* __restrict__ wctu, const float* __restrict__ bc2,
        float* __restrict__ sbuf, float* __restrict__ stats)
{
    __shared__ unsigned short Al[64][72];
    __shared__ unsigned short Bl[16][72];
    const int bid = blockIdx.x, tid = threadIdx.x;
    const int lane = tid & 63, w = tid >> 6;
    const int n0 = bid*8;
    f32x4_t acc = {0.f,0.f,0.f,0.f};
    for (int step = 0; step < 40; ++step){
        int k0 = step*64;
        #pragma unroll
        for (int ld = 0; ld < 2; ++ld){
            int idx = tid + ld*256;
            int row = idx >> 3, kg = (idx & 7)*8;
            uint4 av;
            if (k0 < 512) av = *reinterpret_cast<const uint4*>(&attu[(size_t)row*DA + k0 + kg]);
            else          av = *reinterpret_cast<const uint4*>(&actu[(size_t)row*DM + (k0-512) + kg]);
            *reinterpret_cast<uint4*>(&Al[row][kg]) = av;
        }
        if (tid < 128){
            int row = tid >> 3, kg = (tid & 7)*8;
            size_t nr = (row < 8) ? (size_t)(n0 + row) : (size_t)(2048 + n0 + row - 8);
            *reinterpret_cast<uint4*>(&Bl[row][kg]) =
                *reinterpret_cast<const uint4*>(&wctu[nr*KTOT + k0 + kg]);
        }
        __syncthreads();
        int arow = w*16 + (lane & 15);
        int koff = (lane >> 4)*8;
        bf16x8_t a0 = *reinterpret_cast<const bf16x8_t*>(&Al[arow][koff]);
        bf16x8_t a1 = *reinterpret_cast<const bf16x8_t*>(&Al[arow][32 + koff]);
        int brow = lane & 15;
        bf16x8_t b0 = *reinterpret_cast<const bf16x8_t*>(&Bl[brow][koff]);
        bf16x8_t b1 = *reinterpret_cast<const bf16x8_t*>(&Bl[brow][32 + koff]);
        acc = __builtin_amdgcn_mfma_f32_16x16x32_bf16(a0, b0, acc, 0, 0, 0);
        acc = __builtin_amdgcn_mfma_f32_16x16x32_bf16(a1, b1, acc, 0, 0, 0);
        __syncthreads();
    }
    // epilogue: lanes colb<8 hold h1(col n0+colb); colb>=8 hold h2(col n0+colb-8)
    int colb = lane & 15, rg4 = (lane >> 4)*4;
    int nn = n0 + (colb & 7);
    float b1v = bc2[nn], b2v = bc2[2048 + nn];
    #pragma unroll
    for (int r = 0; r < 4; ++r){
        float v  = acc[r];
        float vo = __shfl_xor(v, 8, 64);
        float h1 = ((colb < 8) ? v : vo) + b1v;
        float h2 = ((colb < 8) ? vo : v) + b2v;
        float sv = h1 * (1.f/(1.f + __expf(-h2)));
        int b = w*16 + rg4 + r;
        if (colb < 8) sbuf[(size_t)b*DM + nn] = sv;
        float ps = sv, pq = sv*sv;
        #pragma unroll
        for (int o = 1; o < 8; o <<= 1){ ps += __shfl_xor(ps, o, 64); pq += __shfl_xor(pq, o, 64); }
        if (colb == 0){
            atomicAdd(&stats[b*2], ps);
            atomicAdd(&stats[b*2 + 1], pq);
        }
    }
}

// nlm: wave w handles d = bid*8+w; lane = batch.  Finalizes LN from raw sums.
__global__ __launch_bounds__(512) void nlm2(
        const float* __restrict__ sbuf, const float* __restrict__ stats,
        const float* __restrict__ lng, const float* __restrict__ lnb,
        unsigned short* __restrict__ traceb, const float* __restrict__ stt,
        const unsigned short* __restrict__ nw1b, const float* __restrict__ nb1,
        const float* __restrict__ nw2, const float* __restrict__ nb2,
        float* __restrict__ act_f, unsigned short* __restrict__ act_bf, int t)
{
    __shared__ float wall[8*864];
    const int tid = threadIdx.x, lane = tid & 63, w = tid >> 6;
    const int d = blockIdx.x*8 + w;
    float* wreg = wall + (size_t)w*864;     // [800 w1][32 nb1][32 nw2]
    for (int i = lane; i < 800; i += 64) wreg[i] = bfs2f(nw1b[(size_t)d*800 + i]);
    if (lane < 32) wreg[800 + lane] = nb1[d*HN + lane];
    else           wreg[832 + (lane - 32)] = nw2[d*HN + (lane - 32)];
    float ssum = stats[lane*2], ssq = stats[lane*2 + 1];
    float mu  = ssum*(1.0f/DM);
    float inv = rsqrtf(fmaxf(ssq*(1.0f/DM) - mu*mu, 0.f) + 1e-5f);
    float s   = sbuf[(size_t)lane*DM + d];
    float st  = (s - mu)*inv*lng[d] + lnb[d];
    int slot = t % MM;
    traceb[((size_t)slot*DM + d)*BB + lane] = f2bfu(st);
    float tr[25];
    #pragma unroll
    for (int m = 0; m < 24; ++m){
        int time = t - 24 + m;
        tr[m] = (time >= 0) ? bfs2f(traceb[((size_t)(time % MM)*DM + d)*BB + lane])
                            : stt[(size_t)d*MM + (m + t + 1)];
    }
    tr[24] = st;
    float a[32];
    #pragma unroll
    for (int h = 0; h < 32; ++h) a[h] = wreg[800 + h];
    #pragma unroll
    for (int m = 0; m < 25; ++m){
        float tm = tr[m];
        #pragma unroll
        for (int q4 = 0; q4 < 8; ++q4){
            float4 w4 = *(const float4*)&wreg[m*32 + q4*4];
            a[q4*4+0] += tm*w4.x;
            a[q4*4+1] += tm*w4.y;
            a[q4*4+2] += tm*w4.z;
            a[q4*4+3] += tm*w4.w;
        }
    }
    float pa = 0.f;
    #pragma unroll
    for (int h = 0; h < 32; ++h) pa += gelu_tanh(a[h])*wreg[832 + h];
    float v = pa + nb2[d];
    act_f[(size_t)d*BB + lane] = v;
    act_bf[(size_t)lane*DM + d] = f2bfu(v);
}

// ---------------- post-loop kernels ----------------
__global__ void entropy_k(const unsigned short* __restrict__ predA, float* __restrict__ out_cert)
{
    __shared__ float red[8];
    int b = blockIdx.x & 63, t = blockIdx.x >> 6, tid = threadIdx.x;
    const unsigned short* pr = predA + (size_t)t*BB*NPAD + (size_t)b*NPAD;
    float v[4];
    float m = -1e30f;
    #pragma unroll
    for (int i = 0; i < 4; ++i){
        int n = tid + i*256;
        v[i] = (n < NOUT) ? bfs2f(pr[n]) : -1e30f;
        m = fmaxf(m, v[i]);
    }
    for (int o = 32; o; o >>= 1) m = fmaxf(m, __shfl_xor(m, o, 64));
    if ((tid & 63) == 0) red[tid >> 6] = m;
    __syncthreads();
    m = fmaxf(fmaxf(red[0], red[1]), fmaxf(red[2], red[3]));
    __syncthreads();
    float s1 = 0.f, s2 = 0.f;
    #pragma unroll
    for (int i = 0; i < 4; ++i){
        int n = tid + i*256;
        if (n < NOUT){
            float e = __expf(v[i] - m);
            s1 += e; s2 += e*(v[i] - m);
        }
    }
    for (int o = 32; o; o >>= 1){ s1 += __shfl_xor(s1, o, 64); s2 += __shfl_xor(s2, o, 64); }
    if ((tid & 63) == 0){ red[tid >> 6] = s1; red[4 + (tid >> 6)] = s2; }
    __syncthreads();
    s1 = red[0]+red[1]+red[2]+red[3];
    s2 = red[4]+red[5]+red[6]+red[7];
    float plogp = s2/s1 - logf(s1);
    float ne = -plogp / logf((float)NOUT);
    if (tid == 0){
        out_cert[(size_t)b*2*TT + t]      = ne;
        out_cert[(size_t)b*2*TT + TT + t] = 1.f - ne;
    }
}

__global__ void transpose_pred(const unsigned short* __restrict__ predA, float* __restrict__ out_pred)
{
    __shared__ unsigned short sm[50][136];
    int bx = blockIdx.x;
    int b  = blockIdx.y;
    int tid = threadIdx.x;
    for (int tp = 0; tp < 25; ++tp){
        int t = tp*2 + (tid >> 7);
        int nn = tid & 127;
        sm[t][nn] = predA[(size_t)t*BB*NPAD + (size_t)b*NPAD + bx*128 + nn];
    }
    __syncthreads();
    int nloc = tid >> 1, half = tid & 1;
    int n = bx*128 + nloc;
    if (n < NOUT){
        float* dst = out_pred + (size_t)b*NOUT*TT + (size_t)n*TT + half*25;
        #pragma unroll
        for (int q = 0; q < 25; ++q) dst[q] = bfs2f(sm[half*25 + q][nloc]);
    }
}

extern "C" void kernel_launch(void* const* d_in, const int* in_sizes, int n_in,
                              void* d_out, int out_size, void* d_ws, size_t ws_size,
                              hipStream_t stream)
{
    const float* x    = (const float*)d_in[0];
    const float* Wf   = (const float*)d_in[1];
    const float* bf   = (const float*)d_in[2];
    const float* stt  = (const float*)d_in[3];
    const float* ss   = (const float*)d_in[4];
    const float* dca  = (const float*)d_in[5];
    const float* dco  = (const float*)d_in[6];
    const float* Wqp  = (const float*)d_in[7];
    const float* bqp  = (const float*)d_in[8];
    const float* Wq   = (const float*)d_in[9];
    const float* bq   = (const float*)d_in[10];
    const float* Wk   = (const float*)d_in[11];
    const float* bk   = (const float*)d_in[12];
    const float* Wv   = (const float*)d_in[13];
    const float* bv   = (const float*)d_in[14];
    const float* Wo   = (const float*)d_in[15];
    const float* bo   = (const float*)d_in[16];
    const float* Ws1  = (const float*)d_in[17];
    const float* bs1  = (const float*)d_in[18];
    const float* lng  = (const float*)d_in[19];
    const float* lnb  = (const float*)d_in[20];
    const float* nw1  = (const float*)d_in[21];
    const float* nb1  = (const float*)d_in[22];
    const float* nw2  = (const float*)d_in[23];
    const float* nb2  = (const float*)d_in[24];
    const float* Wout = (const float*)d_in[25];
    const float* bout = (const float*)d_in[26];
    const int* ila = (const int*)d_in[27];
    const int* ira = (const int*)d_in[28];
    const int* ilo = (const int*)d_in[29];
    const int* iro = (const int*)d_in[30];

    float* ws = (float*)d_ws;
    unsigned short* Kb    = (unsigned short*)(ws + OFF_K);
    unsigned short* Vb    = (unsigned short*)(ws + OFF_V);
    unsigned short* WcT   = (unsigned short*)(ws + OFF_WCT);
    unsigned short* Wc1b  = (unsigned short*)(ws + OFF_WC1B);
    unsigned short* WoutT = (unsigned short*)(ws + OFF_WOUTT);
    unsigned short* nw1b  = (unsigned short*)(ws + OFF_NW1B);
    unsigned short* WfT   = (unsigned short*)(ws + OFF_WFT);
    unsigned short* WkT   = (unsigned short*)(ws + OFF_WKT);
    unsigned short* WvT   = (unsigned short*)(ws + OFF_WVT);
    unsigned short* WqT   = (unsigned short*)(ws + OFF_WQT);
    unsigned short* Wqpb  = (unsigned short*)(ws + OFF_WQPB);
    unsigned short* Wob   = (unsigned short*)(ws + OFF_WOB);
    unsigned short* xb    = (unsigned short*)(ws + OFF_XB);
    unsigned short* kvb   = (unsigned short*)(ws + OFF_KV);
    unsigned short* Ws1T  = (unsigned short*)(ws + OFF_WS1T);
    float* bc1   = ws + OFF_BC1;
    float* bc2   = ws + OFF_BC2;
    float* boutp = ws + OFF_BOUTP;
    float* aA    = ws + OFF_AA;
    float* bA    = ws + OFF_BA;
    float* aO    = ws + OFF_AO;
    float* bO    = ws + OFF_BO;
    unsigned short* attb  = (unsigned short*)(ws + OFF_ATT);
    unsigned short* actb  = (unsigned short*)(ws + OFF_ACTB);
    float* actf  = ws + OFF_ACTF;
    float* sbuf  = ws + OFF_SBUF;
    float* stats = ws + OFF_STATS;
    unsigned short* traceb = (unsigned short*)(ws + OFF_TRB);
    unsigned short* predA  = (unsigned short*)(ws + OFF_PREDA);

    float* outp = (float*)d_out;
    float* out_pred = outp;
    float* out_cert = outp + (size_t)BB*NOUT*TT;
    float* out_syo  = out_cert + (size_t)BB*2*TT;

    // ---- setup (order matters: xb/kvb/Ws1T alias tick-time buffers) ----
    cvt_bf16<<<8192, 256, 0, stream>>>(x, xb, 4096*512);
    tcvtb<<<dim3(16,16), 256, 0, stream>>>(Wf, 512, WfT, 512);
    tcvtb<<<dim3(16,16), 256, 0, stream>>>(Wk, 512, WkT, 512);
    tcvtb<<<dim3(16,16), 256, 0, stream>>>(Wv, 512, WvT, 512);
    tcvtb<<<dim3(16,16), 256, 0, stream>>>(Wq, 512, WqT, 512);
    cvt_bf16<<<1024, 256, 0, stream>>>(Wqp, Wqpb, 512*512);
    cvt_bf16<<<1024, 256, 0, stream>>>(Wo, Wob, 512*512);
    cvt_bf16<<<6400, 256, 0, stream>>>(nw1, nw1b, DM*MM*HN);
    mgemm<<<dim3(8,64), 256, 0, stream>>>(xb, 512, WfT, 512, bf, kvb, 512, 512);
    mgemm<<<dim3(8,64), 256, 0, stream>>>(kvb, 512, WkT, 512, bk, Kb, 512, 512);
    mgemm<<<dim3(8,64), 256, 0, stream>>>(kvb, 512, WvT, 512, bv, Vb, 512, 512);
    mgemm<<<dim3(8,8),  256, 0, stream>>>(Wqpb, 512, WqT, 512, nullptr, Wc1b, 512, 512);
    tcvtb<<<dim3(128,16), 256, 0, stream>>>(Ws1, NOUT2, Ws1T, 512);   // kvb dead now
    mgemm<<<dim3(8,64), 256, 0, stream>>>(Ws1T, 512, Wob, 512, nullptr, WcT, KTOT, 512);
    tcvt_ws1<<<dim3(128,64), 256, 0, stream>>>(Ws1, WcT);
    tcvt_wout<<<NPAD, 256, 0, stream>>>(Wout, bout, WoutT, boutp);
    bias_combo<<<2, 256, 0, stream>>>(bqp, Wq, 512, bq, bc1, 512);
    bias_combo<<<16,256, 0, stream>>>(bo,  Ws1, NOUT2, bs1, bc2, 4096);
    init_state<<<512, 256, 0, stream>>>(ss, ilo, iro, actf, actb, aA, bA, aO, bO);

    // ---- tick loop: 3 launches per tick ----
    for (int t = 0; t < TT; ++t){
        tick_head<<<80, 512, 0, stream>>>(actf, aA, bA, aO, bO,
                                          ila, ira, ilo, iro, dca, dco,
                                          Wc1b, bc1, Kb, Vb, attb,
                                          WoutT, boutp, predA, out_syo, stats,
                                          t, (t > 0) ? 1 : 0);
        hgemm_glu<<<256, 256, 0, stream>>>(attb, actb, WcT, bc2, sbuf, stats);
        nlm2<<<256, 512, 0, stream>>>(sbuf, stats, lng, lnb, traceb, stt,
                                      nw1b, nb1, nw2, nb2, actf, actb, t);
    }
    pred_fin<<<16, 512, 0, stream>>>(actf, aO, bO, ilo, iro, dco,
                                     WoutT, boutp, predA, out_syo);

    // ---- outputs ----
    entropy_k<<<TT*BB, 256, 0, stream>>>(predA, out_cert);
    transpose_pred<<<dim3(8, BB), 256, 0, stream>>>(predA, out_pred);
}